// Round 4
// baseline (460.440 us; speedup 1.0000x reference)
//
#include <hip/hip_runtime.h>
#include <hip/hip_bf16.h>

// Problem constants
#define T_TOK 4096   // B*S
#define DD 768
#define HH 3072
#define EE 4
#define LL 2
#define NELT (T_TOK * DD)

typedef __attribute__((ext_vector_type(8))) short short8;
typedef __attribute__((ext_vector_type(4))) float f32x4;

__device__ __forceinline__ float bf2f(ushort u) { return __uint_as_float(((unsigned)u) << 16); }
__device__ __forceinline__ ushort f2bf(float f) {
  unsigned x = __float_as_uint(f);
  return (ushort)((x + 0x7fffu + ((x >> 16) & 1u)) >> 16); // RNE
}

__device__ __forceinline__ void gl2lds16(const void* g, void* l) {
  __builtin_amdgcn_global_load_lds((const __attribute__((address_space(1))) void*)g,
                                   (__attribute__((address_space(3))) void*)l, 16, 0, 0);
}

// ---------------- prep: bucket tokens by expert, 128-row tiles ----------------
// meta: [0..3]=expert offsets, [4]=total, [5]=ntiles, [8+t]=tile_expert, [96+t]=tile_mstart
__global__ __launch_bounds__(256) void prep_kernel(const int* __restrict__ eidx,
                                                   int* __restrict__ inv,
                                                   int* __restrict__ meta) {
  __shared__ int cnt[EE], cur[EE], offs[EE];
  int t = threadIdx.x;
  if (t < EE) { cnt[t] = 0; cur[t] = 0; }
  __syncthreads();
  for (int i = t; i < T_TOK; i += 256) atomicAdd(&cnt[eidx[i]], 1);
  __syncthreads();
  if (t == 0) {
    int off = 0, nt = 0;
    for (int e = 0; e < EE; e++) {
      meta[e] = off; offs[e] = off;
      int c = cnt[e];
      int n = (c + 127) >> 7;
      for (int k = 0; k < n; k++) { meta[8 + nt] = e; meta[96 + nt] = k << 7; nt++; }
      off += c;
    }
    meta[4] = off;
    meta[5] = nt;
  }
  __syncthreads();
  for (int i = t; i < T_TOK; i += 256) {
    int e = eidx[i];
    inv[i] = offs[e] + atomicAdd(&cur[e], 1);
  }
}

// ---------------- LayerNorm (wave/token), optional fused residual partial-sum ----------------
// HASY: v = x[tok] + y0[pos] + y1[pos];  WRITEX: xf[tok] = v.  Writes h[pos] = LN(v).
template <bool HASY, bool WRITEX>
__global__ __launch_bounds__(256) void ln_kernel(const float* __restrict__ x,
                                                 const float* __restrict__ y,
                                                 const float* __restrict__ g,
                                                 const float* __restrict__ b,
                                                 const int* __restrict__ inv,
                                                 ushort* __restrict__ h,
                                                 float* __restrict__ xf) {
  int wid = blockIdx.x * 4 + (threadIdx.x >> 6);
  int lane = threadIdx.x & 63;
  int pos = inv[wid];
  const float* xr = x + (size_t)wid * DD;
  const float* y0 = y + (size_t)pos * DD;
  const float* y1 = y0 + NELT;
  float v[12], s = 0.f, ss = 0.f;
#pragma unroll
  for (int i = 0; i < 12; i++) {
    int c = lane + i * 64;
    float vv = xr[c];
    if (HASY) vv += y0[c] + y1[c];
    if (WRITEX) xf[(size_t)wid * DD + c] = vv;
    v[i] = vv;
    s += vv; ss += vv * vv;
  }
#pragma unroll
  for (int o = 32; o; o >>= 1) { s += __shfl_xor(s, o, 64); ss += __shfl_xor(ss, o, 64); }
  float mu = s * (1.f / DD);
  float var = ss * (1.f / DD) - mu * mu;
  float rs = rsqrtf(var + 1e-6f);
  ushort* hr = h + (size_t)pos * DD;
#pragma unroll
  for (int i = 0; i < 12; i++) {
    int c = lane + i * 64;
    hr[c] = f2bf((v[i] - mu) * rs * g[c] + b[c]);
  }
}

// ---------------- final: out = xf + y0 + y1 (wave/token) ----------------
__global__ __launch_bounds__(256) void store_kernel(const float* __restrict__ xf,
                                                    const float* __restrict__ y,
                                                    const int* __restrict__ inv,
                                                    float* __restrict__ out) {
  int wid = blockIdx.x * 4 + (threadIdx.x >> 6);
  int lane = threadIdx.x & 63;
  int pos = inv[wid];
  const float* xr = xf + (size_t)wid * DD;
  const float* y0 = y + (size_t)pos * DD;
  const float* y1 = y0 + NELT;
  float* o = out + (size_t)wid * DD;
#pragma unroll
  for (int i = 0; i < 12; i++) {
    int c = lane + i * 64;
    o[c] = xr[c] + y0[c] + y1[c];
  }
}

// ---------------- fp32 (R,C) -> bf16 (C,R) transpose+downcast, batched over z ----------------
__global__ __launch_bounds__(256) void transpose_f32_bf16(const float* __restrict__ src,
                                                          ushort* __restrict__ dst,
                                                          int R, int C) {
  __shared__ ushort tile[64][68];
  size_t mo = (size_t)blockIdx.z * R * C;
  src += mo;
  dst += mo;
  int c0 = blockIdx.x * 64, r0 = blockIdx.y * 64;
  int t = threadIdx.x;
  int tr = t >> 4;          // 0..15
  int tc = (t & 15) << 2;   // 0..60 step 4
#pragma unroll
  for (int i = 0; i < 4; i++) {
    int r = tr + i * 16;
    float4 v = *(const float4*)(src + (size_t)(r0 + r) * C + (c0 + tc));
    tile[r][tc] = f2bf(v.x); tile[r][tc + 1] = f2bf(v.y);
    tile[r][tc + 2] = f2bf(v.z); tile[r][tc + 3] = f2bf(v.w);
  }
  __syncthreads();
#pragma unroll
  for (int i = 0; i < 4; i++) {
    int c = tr + i * 16;
    ushort4 v;
    v.x = tile[tc][c]; v.y = tile[tc + 1][c]; v.z = tile[tc + 2][c]; v.w = tile[tc + 3][c];
    *(ushort4*)(dst + (size_t)(c0 + c) * R + (r0 + tc)) = v;
  }
}

// ---------------- grouped GEMM, 128M x 128N tile, BK=64, XOR-swizzled LDS ----------------
// Occupancy round: m97-proven SINGLE-buffer 2-barrier structure (32 KB LDS -> 4 blocks/CU,
// launch_bounds(256,4)) so wave-level TLP overlaps staging/LDS/MFMA (m114) instead of the
// R2/R3 explicit pipeline that cost residency for zero gain. Keeps R3's 128x128 tile
// (2x arithmetic intensity) and XCD-chunked bijective swizzle (FETCH 120->45 MB win).
// A: (T_TOK, KTOT) bf16 PERMUTED rows.  Bt: (E*NTOT, KTOT) bf16.
// GELU=true : a[pos] = gelu(A@B + bias) bf16 (LDS repack, coalesced)
// GELU=false: partial fp32 y[z*NELT + pos*DD + n] = A@B (+bias on split 0), coalesced
template <int KTOT, int KLEN, int NTOT, bool GELU>
__global__ __launch_bounds__(256, 4) void gemm_kernel(const ushort* __restrict__ A,
                                                      const ushort* __restrict__ Bt,
                                                      const float* __restrict__ bias,
                                                      void* __restrict__ Cout,
                                                      const int* __restrict__ meta) {
  // XCD-chunked bijective swizzle over the launched (x,y) grid, per z-slice.
  int gx = gridDim.x;
  int nwg = gx * gridDim.y;
  int wgid = blockIdx.y * gx + blockIdx.x;
  int sq = nwg >> 3, sr = nwg & 7;
  int xcd = wgid & 7, sidx = wgid >> 3;
  int sw = (xcd < sr ? xcd * (sq + 1) : sr * (sq + 1) + (xcd - sr) * sq) + sidx;
  int ntile = sw % gx;
  int ty = sw / gx;

  if (ty >= meta[5]) return;
  int e = meta[8 + ty];
  int mstart = meta[96 + ty];
  int off0 = meta[e];
  int cnt = meta[e + 1] - off0;
  int z = blockIdx.z;
  int kbegin = z * KLEN;

  // 32 KB LDS: As 128x64 + Bs 128x64 bf16, single-buffered. Epilogue repack reuses all 32 KB.
  __shared__ __align__(16) ushort lds[16384];

  int tid = threadIdx.x;
  int w = tid >> 6, lane = tid & 63;

  // staging: row-group rr = lane>>3 (0..7); global chunk = (lane&7) ^ rr (XOR swizzle)
  // so LDS[r][c] holds global chunk (c ^ (r&7)). LDS dest = uniform base + lane*16.
  int rr = lane >> 3;
  int swz = ((lane & 7) ^ rr) * 8; // element offset of the 16B chunk this lane fetches
  const ushort* agp[4];
  const ushort* bgp[4];
  int aoff[4];
  int boff[4];
#pragma unroll
  for (int i = 0; i < 4; i++) {
    int r = w * 32 + i * 8;                       // uniform part of A row (0..127)
    int arow = off0 + min(mstart + r + rr, cnt - 1);
    agp[i] = A + (size_t)arow * KTOT + kbegin + swz;
    aoff[i] = r * 64 + lane * 8;                  // = uniform + lane*16B
  }
#pragma unroll
  for (int i = 0; i < 4; i++) {
    int r = w * 32 + i * 8;                       // B row (0..127)
    int brow = e * NTOT + ntile * 128 + r + rr;
    bgp[i] = Bt + (size_t)brow * KTOT + kbegin + swz;
    boff[i] = 8192 + r * 64 + lane * 8;
  }

  // wave grid 2x2: each wave owns 64M x 64N
  int wm = (w >> 1) * 64, wn = (w & 1) * 64;
  int qm = lane & 15;
  int quad = lane >> 4;
  int s7 = qm & 7;

  f32x4 acc[4][4];
#pragma unroll
  for (int mi = 0; mi < 4; mi++)
#pragma unroll
    for (int ni = 0; ni < 4; ni++) acc[mi][ni] = (f32x4){0.f, 0.f, 0.f, 0.f};

  for (int k0 = 0; k0 < KLEN; k0 += 64) {
#pragma unroll
    for (int i = 0; i < 4; i++) gl2lds16(agp[i] + k0, lds + aoff[i]);
#pragma unroll
    for (int i = 0; i < 4; i++) gl2lds16(bgp[i] + k0, lds + boff[i]);
    __syncthreads();

    const ushort* Asb = lds;
    const ushort* Bsb = lds + 8192;
#pragma unroll
    for (int h2 = 0; h2 < 2; h2++) {
      int lchunk = ((h2 * 4 + quad) ^ s7) * 8;    // un-swizzle
      short8 af[4], bfr[4];
#pragma unroll
      for (int mi = 0; mi < 4; mi++)
        af[mi] = *(const short8*)(Asb + (wm + mi * 16 + qm) * 64 + lchunk);
#pragma unroll
      for (int ni = 0; ni < 4; ni++)
        bfr[ni] = *(const short8*)(Bsb + (wn + ni * 16 + qm) * 64 + lchunk);
#pragma unroll
      for (int mi = 0; mi < 4; mi++)
#pragma unroll
        for (int ni = 0; ni < 4; ni++)
          acc[mi][ni] = __builtin_amdgcn_mfma_f32_16x16x32_bf16(af[mi], bfr[ni], acc[mi][ni], 0, 0, 0);
    }
    __syncthreads();
  }

  // epilogue. C/D mapping: col = lane&15, row = quad*4 + reg
  int rbase = quad * 4;
  float bv[4];
#pragma unroll
  for (int ni = 0; ni < 4; ni++)
    bv[ni] = (!GELU && z != 0) ? 0.f : bias[e * NTOT + ntile * 128 + wn + ni * 16 + qm];

  if (GELU) {
    // bias+gelu -> LDS 128x128 bf16 -> coalesced 16B row stores (permuted space)
#pragma unroll
    for (int mi = 0; mi < 4; mi++)
#pragma unroll
      for (int ni = 0; ni < 4; ni++) {
        int c = wn + ni * 16 + qm;
#pragma unroll
        for (int r = 0; r < 4; r++) {
          float vv = acc[mi][ni][r] + bv[ni];
          vv = 0.5f * vv * (1.f + erff(vv * 0.70710678118f));
          lds[(wm + mi * 16 + rbase + r) * 128 + c] = f2bf(vv);
        }
      }
    __syncthreads();
    int row0 = tid >> 4;            // 0..15
    int cseg = (tid & 15) * 8;      // 16B chunks
    ushort* aout = (ushort*)Cout;
#pragma unroll
    for (int it = 0; it < 8; it++) {
      int row = it * 16 + row0;
      int mg = mstart + row;
      if (mg < cnt) {
        short8 v = *(const short8*)(lds + row * 128 + cseg);
        *(short8*)(aout + (size_t)(off0 + mg) * HH + ntile * 128 + cseg) = v;
      }
    }
  } else {
    // coalesced fp32 partial stores (permuted space), no atomics
    float* y = (float*)Cout + (size_t)z * NELT;
#pragma unroll
    for (int mi = 0; mi < 4; mi++) {
#pragma unroll
      for (int r = 0; r < 4; r++) {
        int mg = mstart + wm + mi * 16 + rbase + r;
        if (mg >= cnt) continue;
        float* crow = y + (size_t)(off0 + mg) * DD + ntile * 128;
#pragma unroll
        for (int ni = 0; ni < 4; ni++)
          crow[wn + ni * 16 + qm] = acc[mi][ni][r] + bv[ni];
      }
    }
  }
}

// ---------------- host ----------------
extern "C" void kernel_launch(void* const* d_in, const int* in_sizes, int n_in,
                              void* d_out, int out_size, void* d_ws, size_t ws_size,
                              hipStream_t stream) {
  const float* x   = (const float*)d_in[0];
  const int*  eidx = (const int*)d_in[1];
  const float* W1  = (const float*)d_in[2];
  const float* b1  = (const float*)d_in[3];
  const float* W2  = (const float*)d_in[4];
  const float* b2  = (const float*)d_in[5];
  const float* lng = (const float*)d_in[6];
  const float* lnb = (const float*)d_in[7];

  char* ws = (char*)d_ws;
  // layout (bytes): xf 12582912 | h 6291456 | a 25165824 | Wt 18874368 | y 25165824 | inv | meta
  float*  xf   = (float*)(ws + 0);
  ushort* h    = (ushort*)(ws + 12582912);
  ushort* a    = (ushort*)(ws + 18874368);
  ushort* Wt   = (ushort*)(ws + 44040192);
  float*  y    = (float*)(ws + 62914560);
  int*    inv  = (int*)(ws + 88080384);
  int*    meta = (int*)(ws + 88096768);

  prep_kernel<<<1, 256, 0, stream>>>(eidx, inv, meta);

  for (int l = 0; l < LL; l++) {
    if (l == 0)
      ln_kernel<false, false><<<T_TOK / 4, 256, 0, stream>>>(
          x, y, lng, lnb, inv, h, xf);
    else
      ln_kernel<true, true><<<T_TOK / 4, 256, 0, stream>>>(
          x, y, lng + l * DD, lnb + l * DD, inv, h, xf);
    // W1 slice (E, D, H) fp32 -> Wt (E, H, D) bf16
    transpose_f32_bf16<<<dim3(HH / 64, DD / 64, EE), 256, 0, stream>>>(
        W1 + (size_t)l * EE * DD * HH, Wt, DD, HH);
    gemm_kernel<DD, DD, HH, true><<<dim3(HH / 128, 35), 256, 0, stream>>>(
        h, Wt, b1 + l * EE * HH, (void*)a, meta);
    // W2 slice (E, H, D) fp32 -> Wt (E, D, H) bf16
    transpose_f32_bf16<<<dim3(DD / 64, HH / 64, EE), 256, 0, stream>>>(
        W2 + (size_t)l * EE * HH * DD, Wt, HH, DD);
    gemm_kernel<HH, HH / 2, DD, false><<<dim3(DD / 128, 35, 2), 256, 0, stream>>>(
        a, Wt, b2 + l * EE * DD, (void*)y, meta);
  }

  store_kernel<<<T_TOK / 4, 256, 0, stream>>>(xf, y, inv, (float*)d_out);
}

// Round 5
// 375.363 us; speedup vs baseline: 1.2267x; 1.2267x over previous
//
#include <hip/hip_runtime.h>
#include <hip/hip_bf16.h>

// Problem constants
#define T_TOK 4096   // B*S
#define DD 768
#define HH 3072
#define EE 4
#define LL 2
#define NELT (T_TOK * DD)

typedef __attribute__((ext_vector_type(8))) short short8;
typedef __attribute__((ext_vector_type(4))) float f32x4;

__device__ __forceinline__ float bf2f(ushort u) { return __uint_as_float(((unsigned)u) << 16); }
__device__ __forceinline__ ushort f2bf(float f) {
  unsigned x = __float_as_uint(f);
  return (ushort)((x + 0x7fffu + ((x >> 16) & 1u)) >> 16); // RNE
}

__device__ __forceinline__ void gl2lds16(const void* g, void* l) {
  __builtin_amdgcn_global_load_lds((const __attribute__((address_space(1))) void*)g,
                                   (__attribute__((address_space(3))) void*)l, 16, 0, 0);
}

// ---------------- prep: bucket tokens by expert; 128-row AND 256-row tile lists ----------------
// meta: [0..3]=expert offsets, [4]=total, [5]=ntiles128, [6]=ntiles256,
//       [8+t]=tile128_expert, [96+t]=tile128_mstart, [160+t]=tile256_expert, [224+t]=tile256_mstart
__global__ __launch_bounds__(256) void prep_kernel(const int* __restrict__ eidx,
                                                   int* __restrict__ inv,
                                                   int* __restrict__ meta) {
  __shared__ int cnt[EE], cur[EE], offs[EE];
  int t = threadIdx.x;
  if (t < EE) { cnt[t] = 0; cur[t] = 0; }
  __syncthreads();
  for (int i = t; i < T_TOK; i += 256) atomicAdd(&cnt[eidx[i]], 1);
  __syncthreads();
  if (t == 0) {
    int off = 0, nt = 0, nt2 = 0;
    for (int e = 0; e < EE; e++) {
      meta[e] = off; offs[e] = off;
      int c = cnt[e];
      int n = (c + 127) >> 7;
      for (int k = 0; k < n; k++) { meta[8 + nt] = e; meta[96 + nt] = k << 7; nt++; }
      int n2 = (c + 255) >> 8;
      for (int k = 0; k < n2; k++) { meta[160 + nt2] = e; meta[224 + nt2] = k << 8; nt2++; }
      off += c;
    }
    meta[4] = off;
    meta[5] = nt;
    meta[6] = nt2;
  }
  __syncthreads();
  for (int i = t; i < T_TOK; i += 256) {
    int e = eidx[i];
    inv[i] = offs[e] + atomicAdd(&cur[e], 1);
  }
}

// ---------------- LayerNorm (wave/token), optional fused residual partial-sum ----------------
// HASY: v = x[tok] + y0[pos] + y1[pos];  WRITEX: xf[tok] = v.  Writes h[pos] = LN(v).
template <bool HASY, bool WRITEX>
__global__ __launch_bounds__(256) void ln_kernel(const float* __restrict__ x,
                                                 const float* __restrict__ y,
                                                 const float* __restrict__ g,
                                                 const float* __restrict__ b,
                                                 const int* __restrict__ inv,
                                                 ushort* __restrict__ h,
                                                 float* __restrict__ xf) {
  int wid = blockIdx.x * 4 + (threadIdx.x >> 6);
  int lane = threadIdx.x & 63;
  int pos = inv[wid];
  const float* xr = x + (size_t)wid * DD;
  const float* y0 = y + (size_t)pos * DD;
  const float* y1 = y0 + NELT;
  float v[12], s = 0.f, ss = 0.f;
#pragma unroll
  for (int i = 0; i < 12; i++) {
    int c = lane + i * 64;
    float vv = xr[c];
    if (HASY) vv += y0[c] + y1[c];
    if (WRITEX) xf[(size_t)wid * DD + c] = vv;
    v[i] = vv;
    s += vv; ss += vv * vv;
  }
#pragma unroll
  for (int o = 32; o; o >>= 1) { s += __shfl_xor(s, o, 64); ss += __shfl_xor(ss, o, 64); }
  float mu = s * (1.f / DD);
  float var = ss * (1.f / DD) - mu * mu;
  float rs = rsqrtf(var + 1e-6f);
  ushort* hr = h + (size_t)pos * DD;
#pragma unroll
  for (int i = 0; i < 12; i++) {
    int c = lane + i * 64;
    hr[c] = f2bf((v[i] - mu) * rs * g[c] + b[c]);
  }
}

// ---------------- final: out = xf + y0 + y1 (wave/token) ----------------
__global__ __launch_bounds__(256) void store_kernel(const float* __restrict__ xf,
                                                    const float* __restrict__ y,
                                                    const int* __restrict__ inv,
                                                    float* __restrict__ out) {
  int wid = blockIdx.x * 4 + (threadIdx.x >> 6);
  int lane = threadIdx.x & 63;
  int pos = inv[wid];
  const float* xr = xf + (size_t)wid * DD;
  const float* y0 = y + (size_t)pos * DD;
  const float* y1 = y0 + NELT;
  float* o = out + (size_t)wid * DD;
#pragma unroll
  for (int i = 0; i < 12; i++) {
    int c = lane + i * 64;
    o[c] = xr[c] + y0[c] + y1[c];
  }
}

// ---------------- fp32 (R,C) -> bf16 (C,R) transpose+downcast, batched over z ----------------
__global__ __launch_bounds__(256) void transpose_f32_bf16(const float* __restrict__ src,
                                                          ushort* __restrict__ dst,
                                                          int R, int C) {
  __shared__ ushort tile[64][68];
  size_t mo = (size_t)blockIdx.z * R * C;
  src += mo;
  dst += mo;
  int c0 = blockIdx.x * 64, r0 = blockIdx.y * 64;
  int t = threadIdx.x;
  int tr = t >> 4;          // 0..15
  int tc = (t & 15) << 2;   // 0..60 step 4
#pragma unroll
  for (int i = 0; i < 4; i++) {
    int r = tr + i * 16;
    float4 v = *(const float4*)(src + (size_t)(r0 + r) * C + (c0 + tc));
    tile[r][tc] = f2bf(v.x); tile[r][tc + 1] = f2bf(v.y);
    tile[r][tc + 2] = f2bf(v.z); tile[r][tc + 3] = f2bf(v.w);
  }
  __syncthreads();
#pragma unroll
  for (int i = 0; i < 4; i++) {
    int c = tr + i * 16;
    ushort4 v;
    v.x = tile[tc][c]; v.y = tile[tc + 1][c]; v.z = tile[tc + 2][c]; v.w = tile[tc + 3][c];
    *(ushort4*)(dst + (size_t)(c0 + c) * R + (r0 + tc)) = v;
  }
}

// ---------------- grouped GEMM, 128M x 128N tile, BK=64, XOR-swizzled LDS (R3-verified) ----------------
// Double-buffered LDS + counted-vmcnt pipeline, 4 waves. Used for GEMM2 (N=768).
template <int KTOT, int KLEN, int NTOT, bool GELU>
__global__ __launch_bounds__(256, 2) void gemm_kernel(const ushort* __restrict__ A,
                                                      const ushort* __restrict__ Bt,
                                                      const float* __restrict__ bias,
                                                      void* __restrict__ Cout,
                                                      const int* __restrict__ meta) {
  // XCD-chunked bijective swizzle over the launched (x,y) grid, per z-slice.
  int gx = gridDim.x;
  int nwg = gx * gridDim.y;
  int wgid = blockIdx.y * gx + blockIdx.x;
  int sq = nwg >> 3, sr = nwg & 7;
  int xcd = wgid & 7, sidx = wgid >> 3;
  int sw = (xcd < sr ? xcd * (sq + 1) : sr * (sq + 1) + (xcd - sr) * sq) + sidx;
  int ntile = sw % gx;
  int ty = sw / gx;

  if (ty >= meta[5]) return;
  int e = meta[8 + ty];
  int mstart = meta[96 + ty];
  int off0 = meta[e];
  int cnt = meta[e + 1] - off0;
  int z = blockIdx.z;
  int kbegin = z * KLEN;

  // 64 KB LDS: 2 buffers x (As 128x64 + Bs 128x64) bf16.
  __shared__ __align__(16) ushort lds[32768];

  int tid = threadIdx.x;
  int w = tid >> 6, lane = tid & 63;

  // staging: row-group rr = lane>>3 (0..7); global chunk = (lane&7) ^ rr (XOR swizzle)
  // so LDS[r][c] holds global chunk (c ^ (r&7)). LDS dest = uniform base + lane*16.
  int rr = lane >> 3;
  int swz = ((lane & 7) ^ rr) * 8; // element offset of the 16B chunk this lane fetches
  const ushort* agp[4];
  const ushort* bgp[4];
  int aoff[4];
  int boff[4];
#pragma unroll
  for (int i = 0; i < 4; i++) {
    int r = w * 32 + i * 8;                       // uniform part of A row (0..127)
    int arow = off0 + min(mstart + r + rr, cnt - 1);
    agp[i] = A + (size_t)arow * KTOT + kbegin + swz;
    aoff[i] = r * 64 + lane * 8;                  // = uniform + lane*16B
  }
#pragma unroll
  for (int i = 0; i < 4; i++) {
    int r = w * 32 + i * 8;                       // B row (0..127)
    int brow = e * NTOT + ntile * 128 + r + rr;
    bgp[i] = Bt + (size_t)brow * KTOT + kbegin + swz;
    boff[i] = 8192 + r * 64 + lane * 8;
  }

  // wave grid 2x2: each wave owns 64M x 64N
  int wm = (w >> 1) * 64, wn = (w & 1) * 64;
  int qm = lane & 15;
  int quad = lane >> 4;
  int s7 = qm & 7;

  f32x4 acc[4][4];
#pragma unroll
  for (int mi = 0; mi < 4; mi++)
#pragma unroll
    for (int ni = 0; ni < 4; ni++) acc[mi][ni] = (f32x4){0.f, 0.f, 0.f, 0.f};

#define STAGE(nb, koff)                                            \
  do {                                                             \
    ushort* _b = lds + (nb) * 16384;                               \
    _Pragma("unroll")                                              \
    for (int _i = 0; _i < 4; _i++) gl2lds16(agp[_i] + (koff), _b + aoff[_i]); \
    _Pragma("unroll")                                              \
    for (int _i = 0; _i < 4; _i++) gl2lds16(bgp[_i] + (koff), _b + boff[_i]); \
  } while (0)

  constexpr int NSTEPS = KLEN / 64;
  STAGE(0, 0);                        // prologue: fill buffer 0
  asm volatile("" ::: "memory");      // pin prologue loads as the OLDEST vmcnt entries

#pragma unroll 1
  for (int s = 0; s < NSTEPS; ++s) {
    int curb = s & 1;
    if (s + 1 < NSTEPS) {
      STAGE(curb ^ 1, (s + 1) * 64);                  // prefetch next K-step
      asm volatile("s_waitcnt vmcnt(8)" ::: "memory"); // my 8 cur-buffer loads done; 8 stay in flight
    } else {
      asm volatile("s_waitcnt vmcnt(0)" ::: "memory");
    }
    __builtin_amdgcn_s_barrier();                      // all waves' cur-buffer staging visible
    asm volatile("" ::: "memory");

    const ushort* Asb = lds + curb * 16384;
    const ushort* Bsb = Asb + 8192;
#pragma unroll
    for (int h2 = 0; h2 < 2; h2++) {
      int lchunk = ((h2 * 4 + quad) ^ s7) * 8;    // un-swizzle
      short8 af[4], bfr[4];
#pragma unroll
      for (int mi = 0; mi < 4; mi++)
        af[mi] = *(const short8*)(Asb + (wm + mi * 16 + qm) * 64 + lchunk);
#pragma unroll
      for (int ni = 0; ni < 4; ni++)
        bfr[ni] = *(const short8*)(Bsb + (wn + ni * 16 + qm) * 64 + lchunk);
#pragma unroll
      for (int mi = 0; mi < 4; mi++)
#pragma unroll
        for (int ni = 0; ni < 4; ni++)
          acc[mi][ni] = __builtin_amdgcn_mfma_f32_16x16x32_bf16(af[mi], bfr[ni], acc[mi][ni], 0, 0, 0);
    }
    asm volatile("" ::: "memory");
    __builtin_amdgcn_s_barrier();                      // cur buffer free for overwrite next iter
    asm volatile("" ::: "memory");
  }
#undef STAGE

  // epilogue. C/D mapping: col = lane&15, row = quad*4 + reg
  int rbase = quad * 4;
  float bv[4];
#pragma unroll
  for (int ni = 0; ni < 4; ni++)
    bv[ni] = (!GELU && z != 0) ? 0.f : bias[e * NTOT + ntile * 128 + wn + ni * 16 + qm];

  if (GELU) {
    // bias+gelu -> LDS 128x128 bf16 -> coalesced 16B row stores (permuted space)
#pragma unroll
    for (int mi = 0; mi < 4; mi++)
#pragma unroll
      for (int ni = 0; ni < 4; ni++) {
        int c = wn + ni * 16 + qm;
#pragma unroll
        for (int r = 0; r < 4; r++) {
          float vv = acc[mi][ni][r] + bv[ni];
          vv = 0.5f * vv * (1.f + erff(vv * 0.70710678118f));
          lds[(wm + mi * 16 + rbase + r) * 128 + c] = f2bf(vv);
        }
      }
    __syncthreads();
    int row0 = tid >> 4;            // 0..15
    int cseg = (tid & 15) * 8;      // 16B chunks
    ushort* aout = (ushort*)Cout;
#pragma unroll
    for (int it = 0; it < 8; it++) {
      int row = it * 16 + row0;
      int mg = mstart + row;
      if (mg < cnt) {
        short8 v = *(const short8*)(lds + row * 128 + cseg);
        *(short8*)(aout + (size_t)(off0 + mg) * HH + ntile * 128 + cseg) = v;
      }
    }
  } else {
    // coalesced fp32 partial stores (permuted space), no atomics
    float* y = (float*)Cout + (size_t)z * NELT;
#pragma unroll
    for (int mi = 0; mi < 4; mi++) {
#pragma unroll
      for (int r = 0; r < 4; r++) {
        int mg = mstart + wm + mi * 16 + rbase + r;
        if (mg >= cnt) continue;
        float* crow = y + (size_t)(off0 + mg) * DD + ntile * 128;
#pragma unroll
        for (int ni = 0; ni < 4; ni++)
          crow[wn + ni * 16 + qm] = acc[mi][ni][r] + bv[ni];
      }
    }
  }
}

// ---------------- grouped GEMM, 256M x 256N tile, 8 waves (2x4), BK=64 ----------------
// Same verified sync structure as gemm_kernel (STAGE -> vmcnt(8) -> barrier -> compute -> barrier),
// scaled to 256^2 / 512 threads: ds_read/FLOP drops 31 -> 23 B/kFLOP (m248 quadrant: ~655 TF).
// GELU path only (used for GEMM1). 128 KB LDS -> 1 block/CU.
template <int KTOT, int KLEN, int NTOT>
__global__ __launch_bounds__(512, 2) void gemm256_kernel(const ushort* __restrict__ A,
                                                         const ushort* __restrict__ Bt,
                                                         const float* __restrict__ bias,
                                                         ushort* __restrict__ aout,
                                                         const int* __restrict__ meta) {
  int gx = gridDim.x;
  int nwg = gx * gridDim.y;
  int wgid = blockIdx.y * gx + blockIdx.x;
  int sq = nwg >> 3, sr = nwg & 7;
  int xcd = wgid & 7, sidx = wgid >> 3;
  int sw = (xcd < sr ? xcd * (sq + 1) : sr * (sq + 1) + (xcd - sr) * sq) + sidx;
  int ntile = sw % gx;
  int ty = sw / gx;

  if (ty >= meta[6]) return;
  int e = meta[160 + ty];
  int mstart = meta[224 + ty];
  int off0 = meta[e];
  int cnt = meta[e + 1] - off0;

  // 128 KB LDS: 2 buffers x (As 256x64 + Bs 256x64) bf16. Epilogue repack reuses all of it.
  __shared__ __align__(16) ushort lds[65536];

  int tid = threadIdx.x;                // 0..511
  int w = tid >> 6, lane = tid & 63;    // w 0..7

  int rr = lane >> 3;
  int swz = ((lane & 7) ^ rr) * 8;
  const ushort* agp[4];
  const ushort* bgp[4];
  int aoff[4];
  int boff[4];
#pragma unroll
  for (int i = 0; i < 4; i++) {
    int r = w * 32 + i * 8;                       // A row 0..255
    int arow = off0 + min(mstart + r + rr, cnt - 1);
    agp[i] = A + (size_t)arow * KTOT + swz;
    aoff[i] = r * 64 + lane * 8;
    int brow = e * NTOT + ntile * 256 + r + rr;   // B row 0..255
    bgp[i] = Bt + (size_t)brow * KTOT + swz;
    boff[i] = 16384 + r * 64 + lane * 8;
  }

  // wave grid 2x4: each wave owns 128M x 64N
  int wm = (w >> 2) * 128, wn = (w & 3) * 64;
  int qm = lane & 15;
  int quad = lane >> 4;
  int s7 = qm & 7;

  f32x4 acc[8][4];
#pragma unroll
  for (int mi = 0; mi < 8; mi++)
#pragma unroll
    for (int ni = 0; ni < 4; ni++) acc[mi][ni] = (f32x4){0.f, 0.f, 0.f, 0.f};

#define STAGE2(nb, koff)                                           \
  do {                                                             \
    ushort* _b = lds + (nb) * 32768;                               \
    _Pragma("unroll")                                              \
    for (int _i = 0; _i < 4; _i++) gl2lds16(agp[_i] + (koff), _b + aoff[_i]); \
    _Pragma("unroll")                                              \
    for (int _i = 0; _i < 4; _i++) gl2lds16(bgp[_i] + (koff), _b + boff[_i]); \
  } while (0)

  constexpr int NSTEPS = KLEN / 64;
  STAGE2(0, 0);
  asm volatile("" ::: "memory");

#pragma unroll 1
  for (int s = 0; s < NSTEPS; ++s) {
    int curb = s & 1;
    if (s + 1 < NSTEPS) {
      STAGE2(curb ^ 1, (s + 1) * 64);
      asm volatile("s_waitcnt vmcnt(8)" ::: "memory");
    } else {
      asm volatile("s_waitcnt vmcnt(0)" ::: "memory");
    }
    __builtin_amdgcn_s_barrier();
    asm volatile("" ::: "memory");

    const ushort* Asb = lds + curb * 32768;
    const ushort* Bsb = Asb + 16384;
#pragma unroll
    for (int h2 = 0; h2 < 2; h2++) {
      int lchunk = ((h2 * 4 + quad) ^ s7) * 8;    // un-swizzle
      short8 bfr[4];
#pragma unroll
      for (int ni = 0; ni < 4; ni++)
        bfr[ni] = *(const short8*)(Bsb + (wn + ni * 16 + qm) * 64 + lchunk);
#pragma unroll
      for (int mi = 0; mi < 8; mi++) {
        short8 af = *(const short8*)(Asb + (wm + mi * 16 + qm) * 64 + lchunk);
#pragma unroll
        for (int ni = 0; ni < 4; ni++)
          acc[mi][ni] = __builtin_amdgcn_mfma_f32_16x16x32_bf16(af, bfr[ni], acc[mi][ni], 0, 0, 0);
      }
    }
    asm volatile("" ::: "memory");
    __builtin_amdgcn_s_barrier();
    asm volatile("" ::: "memory");
  }
#undef STAGE2

  // epilogue: bias+gelu -> LDS 256x256 bf16 (128 KB, reuses both buffers) -> coalesced stores
  int rbase = quad * 4;
  float bv[4];
#pragma unroll
  for (int ni = 0; ni < 4; ni++)
    bv[ni] = bias[e * NTOT + ntile * 256 + wn + ni * 16 + qm];

#pragma unroll
  for (int mi = 0; mi < 8; mi++)
#pragma unroll
    for (int ni = 0; ni < 4; ni++) {
      int c = wn + ni * 16 + qm;
#pragma unroll
      for (int r = 0; r < 4; r++) {
        float vv = acc[mi][ni][r] + bv[ni];
        vv = 0.5f * vv * (1.f + erff(vv * 0.70710678118f));
        lds[(wm + mi * 16 + rbase + r) * 256 + c] = f2bf(vv);
      }
    }
  __syncthreads();
  int row0 = tid >> 5;            // 0..15
  int cseg = (tid & 31) * 8;      // 0..248, 16B chunks over 256 cols
#pragma unroll
  for (int it = 0; it < 16; it++) {
    int row = it * 16 + row0;
    int mg = mstart + row;
    if (mg < cnt) {
      short8 v = *(const short8*)(lds + row * 256 + cseg);
      *(short8*)(aout + (size_t)(off0 + mg) * HH + ntile * 256 + cseg) = v;
    }
  }
}

// ---------------- host ----------------
extern "C" void kernel_launch(void* const* d_in, const int* in_sizes, int n_in,
                              void* d_out, int out_size, void* d_ws, size_t ws_size,
                              hipStream_t stream) {
  const float* x   = (const float*)d_in[0];
  const int*  eidx = (const int*)d_in[1];
  const float* W1  = (const float*)d_in[2];
  const float* b1  = (const float*)d_in[3];
  const float* W2  = (const float*)d_in[4];
  const float* b2  = (const float*)d_in[5];
  const float* lng = (const float*)d_in[6];
  const float* lnb = (const float*)d_in[7];

  char* ws = (char*)d_ws;
  // layout (bytes): xf 12582912 | h 6291456 | a 25165824 | Wt 18874368 | y 25165824 | inv | meta
  float*  xf   = (float*)(ws + 0);
  ushort* h    = (ushort*)(ws + 12582912);
  ushort* a    = (ushort*)(ws + 18874368);
  ushort* Wt   = (ushort*)(ws + 44040192);
  float*  y    = (float*)(ws + 62914560);
  int*    inv  = (int*)(ws + 88080384);
  int*    meta = (int*)(ws + 88096768);

  prep_kernel<<<1, 256, 0, stream>>>(eidx, inv, meta);

  for (int l = 0; l < LL; l++) {
    if (l == 0)
      ln_kernel<false, false><<<T_TOK / 4, 256, 0, stream>>>(
          x, y, lng, lnb, inv, h, xf);
    else
      ln_kernel<true, true><<<T_TOK / 4, 256, 0, stream>>>(
          x, y, lng + l * DD, lnb + l * DD, inv, h, xf);
    // W1 slice (E, D, H) fp32 -> Wt (E, H, D) bf16
    transpose_f32_bf16<<<dim3(HH / 64, DD / 64, EE), 256, 0, stream>>>(
        W1 + (size_t)l * EE * DD * HH, Wt, DD, HH);
    // GEMM1: 256^2 8-wave kernel (grid 12 x up-to-19 tiles)
    gemm256_kernel<DD, DD, HH><<<dim3(HH / 256, 19), 512, 0, stream>>>(
        h, Wt, b1 + l * EE * HH, a, meta);
    // W2 slice (E, H, D) fp32 -> Wt (E, D, H) bf16
    transpose_f32_bf16<<<dim3(DD / 64, HH / 64, EE), 256, 0, stream>>>(
        W2 + (size_t)l * EE * HH * DD, Wt, HH, DD);
    // GEMM2: R3-verified 128^2 kernel (control)
    gemm_kernel<HH, HH / 2, DD, false><<<dim3(DD / 128, 35, 2), 256, 0, stream>>>(
        a, Wt, b2 + l * EE * DD, (void*)y, meta);
  }

  store_kernel<<<T_TOK / 4, 256, 0, stream>>>(xf, y, inv, (float*)d_out);
}

// Round 7
// 370.074 us; speedup vs baseline: 1.2442x; 1.0143x over previous
//
#include <hip/hip_runtime.h>
#include <hip/hip_bf16.h>

// Problem constants
#define T_TOK 4096   // B*S
#define DD 768
#define HH 3072
#define EE 4
#define LL 2
#define NELT (T_TOK * DD)

typedef __attribute__((ext_vector_type(8))) short short8;
typedef __attribute__((ext_vector_type(4))) float f32x4;

__device__ __forceinline__ float bf2f(ushort u) { return __uint_as_float(((unsigned)u) << 16); }
__device__ __forceinline__ ushort f2bf(float f) {
  unsigned x = __float_as_uint(f);
  return (ushort)((x + 0x7fffu + ((x >> 16) & 1u)) >> 16); // RNE
}

__device__ __forceinline__ void gl2lds16(const void* g, void* l) {
  __builtin_amdgcn_global_load_lds((const __attribute__((address_space(1))) void*)g,
                                   (__attribute__((address_space(3))) void*)l, 16, 0, 0);
}

// ---------------- prep: bucket tokens by expert, 128-row tiles ----------------
// meta: [0..3]=expert offsets, [4]=total, [5]=ntiles, [8+t]=tile_expert, [96+t]=tile_mstart
__global__ __launch_bounds__(256) void prep_kernel(const int* __restrict__ eidx,
                                                   int* __restrict__ inv,
                                                   int* __restrict__ meta) {
  __shared__ int cnt[EE], cur[EE], offs[EE];
  int t = threadIdx.x;
  if (t < EE) { cnt[t] = 0; cur[t] = 0; }
  __syncthreads();
  for (int i = t; i < T_TOK; i += 256) atomicAdd(&cnt[eidx[i]], 1);
  __syncthreads();
  if (t == 0) {
    int off = 0, nt = 0;
    for (int e = 0; e < EE; e++) {
      meta[e] = off; offs[e] = off;
      int c = cnt[e];
      int n = (c + 127) >> 7;
      for (int k = 0; k < n; k++) { meta[8 + nt] = e; meta[96 + nt] = k << 7; nt++; }
      off += c;
    }
    meta[4] = off;
    meta[5] = nt;
  }
  __syncthreads();
  for (int i = t; i < T_TOK; i += 256) {
    int e = eidx[i];
    inv[i] = offs[e] + atomicAdd(&cur[e], 1);
  }
}

// ---------------- LayerNorm (wave/token), optional fused residual partial-sum ----------------
// HASY: v = x[tok] + y0[pos] + y1[pos];  WRITEX: xf[tok] = v.  Writes h[pos] = LN(v).
template <bool HASY, bool WRITEX>
__global__ __launch_bounds__(256) void ln_kernel(const float* __restrict__ x,
                                                 const float* __restrict__ y,
                                                 const float* __restrict__ g,
                                                 const float* __restrict__ b,
                                                 const int* __restrict__ inv,
                                                 ushort* __restrict__ h,
                                                 float* __restrict__ xf) {
  int wid = blockIdx.x * 4 + (threadIdx.x >> 6);
  int lane = threadIdx.x & 63;
  int pos = inv[wid];
  const float* xr = x + (size_t)wid * DD;
  const float* y0 = y + (size_t)pos * DD;
  const float* y1 = y0 + NELT;
  float v[12], s = 0.f, ss = 0.f;
#pragma unroll
  for (int i = 0; i < 12; i++) {
    int c = lane + i * 64;
    float vv = xr[c];
    if (HASY) vv += y0[c] + y1[c];
    if (WRITEX) xf[(size_t)wid * DD + c] = vv;
    v[i] = vv;
    s += vv; ss += vv * vv;
  }
#pragma unroll
  for (int o = 32; o; o >>= 1) { s += __shfl_xor(s, o, 64); ss += __shfl_xor(ss, o, 64); }
  float mu = s * (1.f / DD);
  float var = ss * (1.f / DD) - mu * mu;
  float rs = rsqrtf(var + 1e-6f);
  ushort* hr = h + (size_t)pos * DD;
#pragma unroll
  for (int i = 0; i < 12; i++) {
    int c = lane + i * 64;
    hr[c] = f2bf((v[i] - mu) * rs * g[c] + b[c]);
  }
}

// ---------------- final: out = xf + y0 + y1 (wave/token) ----------------
__global__ __launch_bounds__(256) void store_kernel(const float* __restrict__ xf,
                                                    const float* __restrict__ y,
                                                    const int* __restrict__ inv,
                                                    float* __restrict__ out) {
  int wid = blockIdx.x * 4 + (threadIdx.x >> 6);
  int lane = threadIdx.x & 63;
  int pos = inv[wid];
  const float* xr = xf + (size_t)wid * DD;
  const float* y0 = y + (size_t)pos * DD;
  const float* y1 = y0 + NELT;
  float* o = out + (size_t)wid * DD;
#pragma unroll
  for (int i = 0; i < 12; i++) {
    int c = lane + i * 64;
    o[c] = xr[c] + y0[c] + y1[c];
  }
}

// ---------------- fp32 (R,C) -> bf16 (C,R) transpose+downcast, batched over z ----------------
// (fallback path: per-layer, per-weight, z = expert)
__global__ __launch_bounds__(256) void transpose_f32_bf16(const float* __restrict__ src,
                                                          ushort* __restrict__ dst,
                                                          int R, int C) {
  __shared__ ushort tile[64][68];
  size_t mo = (size_t)blockIdx.z * R * C;
  src += mo;
  dst += mo;
  int c0 = blockIdx.x * 64, r0 = blockIdx.y * 64;
  int t = threadIdx.x;
  int tr = t >> 4;          // 0..15
  int tc = (t & 15) << 2;   // 0..60 step 4
#pragma unroll
  for (int i = 0; i < 4; i++) {
    int r = tr + i * 16;
    float4 v = *(const float4*)(src + (size_t)(r0 + r) * C + (c0 + tc));
    tile[r][tc] = f2bf(v.x); tile[r][tc + 1] = f2bf(v.y);
    tile[r][tc + 2] = f2bf(v.z); tile[r][tc + 3] = f2bf(v.w);
  }
  __syncthreads();
#pragma unroll
  for (int i = 0; i < 4; i++) {
    int c = tr + i * 16;
    ushort4 v;
    v.x = tile[tc][c]; v.y = tile[tc + 1][c]; v.z = tile[tc + 2][c]; v.w = tile[tc + 3][c];
    *(ushort4*)(dst + (size_t)(c0 + c) * R + (r0 + tc)) = v;
  }
}

// ---------------- ALL weight transposes in ONE dispatch (big-ws path) ----------------
// blockIdx.y = z in [0,16): l = z>>3, w12 = (z>>2)&1 (0:W1, 1:W2), e = z&3.
// W1 slice (l,e): (DD,HH) fp32 -> slot (l*2+0), e: (HH,DD) bf16
// W2 slice (l,e): (HH,DD) fp32 -> slot (l*2+1), e: (DD,HH) bf16
// blockIdx.x = b in [0,576): within-slice tile, gx = C/64 tiles per row-band.
__global__ __launch_bounds__(256) void transpose_all_kernel(const float* __restrict__ W1,
                                                            const float* __restrict__ W2,
                                                            ushort* __restrict__ Wt) {
  __shared__ ushort tile[64][68];
  int z = blockIdx.y;
  int l = z >> 3, w12 = (z >> 2) & 1, e = z & 3;
  int R = w12 ? HH : DD, C = w12 ? DD : HH;
  const float* src = (w12 ? W2 : W1) + (size_t)(l * EE + e) * DD * HH;
  ushort* dst = Wt + ((size_t)(l * 2 + w12) * EE + e) * ((size_t)DD * HH);
  int gx = C >> 6;
  int b = blockIdx.x;
  int c0 = (b % gx) << 6, r0 = (b / gx) << 6;
  int t = threadIdx.x;
  int tr = t >> 4;
  int tc = (t & 15) << 2;
#pragma unroll
  for (int i = 0; i < 4; i++) {
    int r = tr + i * 16;
    float4 v = *(const float4*)(src + (size_t)(r0 + r) * C + (c0 + tc));
    tile[r][tc] = f2bf(v.x); tile[r][tc + 1] = f2bf(v.y);
    tile[r][tc + 2] = f2bf(v.z); tile[r][tc + 3] = f2bf(v.w);
  }
  __syncthreads();
#pragma unroll
  for (int i = 0; i < 4; i++) {
    int c = tr + i * 16;
    ushort4 v;
    v.x = tile[tc][c]; v.y = tile[tc + 1][c]; v.z = tile[tc + 2][c]; v.w = tile[tc + 3][c];
    *(ushort4*)(dst + (size_t)(c0 + c) * R + (r0 + tc)) = v;
  }
}

// ---------------- grouped GEMM, 128M x 128N tile, BK=64, XOR-swizzled LDS (R3-verified) ----------------
// Double-buffered LDS + counted-vmcnt pipeline, 4 waves, 2 blocks/CU.
template <int KTOT, int KLEN, int NTOT, bool GELU>
__global__ __launch_bounds__(256, 2) void gemm_kernel(const ushort* __restrict__ A,
                                                      const ushort* __restrict__ Bt,
                                                      const float* __restrict__ bias,
                                                      void* __restrict__ Cout,
                                                      const int* __restrict__ meta) {
  // XCD-chunked bijective swizzle over the launched (x,y) grid, per z-slice.
  int gx = gridDim.x;
  int nwg = gx * gridDim.y;
  int wgid = blockIdx.y * gx + blockIdx.x;
  int sq = nwg >> 3, sr = nwg & 7;
  int xcd = wgid & 7, sidx = wgid >> 3;
  int sw = (xcd < sr ? xcd * (sq + 1) : sr * (sq + 1) + (xcd - sr) * sq) + sidx;
  int ntile = sw % gx;
  int ty = sw / gx;

  if (ty >= meta[5]) return;
  int e = meta[8 + ty];
  int mstart = meta[96 + ty];
  int off0 = meta[e];
  int cnt = meta[e + 1] - off0;
  int z = blockIdx.z;
  int kbegin = z * KLEN;

  // 64 KB LDS: 2 buffers x (As 128x64 + Bs 128x64) bf16.
  __shared__ __align__(16) ushort lds[32768];

  int tid = threadIdx.x;
  int w = tid >> 6, lane = tid & 63;

  // staging: row-group rr = lane>>3 (0..7); global chunk = (lane&7) ^ rr (XOR swizzle)
  // so LDS[r][c] holds global chunk (c ^ (r&7)). LDS dest = uniform base + lane*16.
  int rr = lane >> 3;
  int swz = ((lane & 7) ^ rr) * 8; // element offset of the 16B chunk this lane fetches
  const ushort* agp[4];
  const ushort* bgp[4];
  int aoff[4];
  int boff[4];
#pragma unroll
  for (int i = 0; i < 4; i++) {
    int r = w * 32 + i * 8;                       // uniform part of A row (0..127)
    int arow = off0 + min(mstart + r + rr, cnt - 1);
    agp[i] = A + (size_t)arow * KTOT + kbegin + swz;
    aoff[i] = r * 64 + lane * 8;                  // = uniform + lane*16B
  }
#pragma unroll
  for (int i = 0; i < 4; i++) {
    int r = w * 32 + i * 8;                       // B row (0..127)
    int brow = e * NTOT + ntile * 128 + r + rr;
    bgp[i] = Bt + (size_t)brow * KTOT + kbegin + swz;
    boff[i] = 8192 + r * 64 + lane * 8;
  }

  // wave grid 2x2: each wave owns 64M x 64N
  int wm = (w >> 1) * 64, wn = (w & 1) * 64;
  int qm = lane & 15;
  int quad = lane >> 4;
  int s7 = qm & 7;

  f32x4 acc[4][4];
#pragma unroll
  for (int mi = 0; mi < 4; mi++)
#pragma unroll
    for (int ni = 0; ni < 4; ni++) acc[mi][ni] = (f32x4){0.f, 0.f, 0.f, 0.f};

#define STAGE(nb, koff)                                            \
  do {                                                             \
    ushort* _b = lds + (nb) * 16384;                               \
    _Pragma("unroll")                                              \
    for (int _i = 0; _i < 4; _i++) gl2lds16(agp[_i] + (koff), _b + aoff[_i]); \
    _Pragma("unroll")                                              \
    for (int _i = 0; _i < 4; _i++) gl2lds16(bgp[_i] + (koff), _b + boff[_i]); \
  } while (0)

  constexpr int NSTEPS = KLEN / 64;
  STAGE(0, 0);                        // prologue: fill buffer 0
  asm volatile("" ::: "memory");      // pin prologue loads as the OLDEST vmcnt entries

#pragma unroll 1
  for (int s = 0; s < NSTEPS; ++s) {
    int curb = s & 1;
    if (s + 1 < NSTEPS) {
      STAGE(curb ^ 1, (s + 1) * 64);                  // prefetch next K-step
      asm volatile("s_waitcnt vmcnt(8)" ::: "memory"); // my 8 cur-buffer loads done; 8 stay in flight
    } else {
      asm volatile("s_waitcnt vmcnt(0)" ::: "memory");
    }
    __builtin_amdgcn_s_barrier();                      // all waves' cur-buffer staging visible
    asm volatile("" ::: "memory");

    const ushort* Asb = lds + curb * 16384;
    const ushort* Bsb = Asb + 8192;
#pragma unroll
    for (int h2 = 0; h2 < 2; h2++) {
      int lchunk = ((h2 * 4 + quad) ^ s7) * 8;    // un-swizzle
      short8 af[4], bfr[4];
#pragma unroll
      for (int mi = 0; mi < 4; mi++)
        af[mi] = *(const short8*)(Asb + (wm + mi * 16 + qm) * 64 + lchunk);
#pragma unroll
      for (int ni = 0; ni < 4; ni++)
        bfr[ni] = *(const short8*)(Bsb + (wn + ni * 16 + qm) * 64 + lchunk);
#pragma unroll
      for (int mi = 0; mi < 4; mi++)
#pragma unroll
        for (int ni = 0; ni < 4; ni++)
          acc[mi][ni] = __builtin_amdgcn_mfma_f32_16x16x32_bf16(af[mi], bfr[ni], acc[mi][ni], 0, 0, 0);
    }
    asm volatile("" ::: "memory");
    __builtin_amdgcn_s_barrier();                      // cur buffer free for overwrite next iter
    asm volatile("" ::: "memory");
  }
#undef STAGE

  // epilogue. C/D mapping: col = lane&15, row = quad*4 + reg
  int rbase = quad * 4;
  float bv[4];
#pragma unroll
  for (int ni = 0; ni < 4; ni++)
    bv[ni] = (!GELU && z != 0) ? 0.f : bias[e * NTOT + ntile * 128 + wn + ni * 16 + qm];

  if (GELU) {
    // bias+gelu -> LDS 128x128 bf16 -> coalesced 16B row stores (permuted space)
#pragma unroll
    for (int mi = 0; mi < 4; mi++)
#pragma unroll
      for (int ni = 0; ni < 4; ni++) {
        int c = wn + ni * 16 + qm;
#pragma unroll
        for (int r = 0; r < 4; r++) {
          float vv = acc[mi][ni][r] + bv[ni];
          vv = 0.5f * vv * (1.f + erff(vv * 0.70710678118f));
          lds[(wm + mi * 16 + rbase + r) * 128 + c] = f2bf(vv);
        }
      }
    __syncthreads();
    int row0 = tid >> 4;            // 0..15
    int cseg = (tid & 15) * 8;      // 16B chunks
    ushort* aout = (ushort*)Cout;
#pragma unroll
    for (int it = 0; it < 8; it++) {
      int row = it * 16 + row0;
      int mg = mstart + row;
      if (mg < cnt) {
        short8 v = *(const short8*)(lds + row * 128 + cseg);
        *(short8*)(aout + (size_t)(off0 + mg) * HH + ntile * 128 + cseg) = v;
      }
    }
  } else {
    // coalesced fp32 partial stores (permuted space), no atomics
    float* y = (float*)Cout + (size_t)z * NELT;
#pragma unroll
    for (int mi = 0; mi < 4; mi++) {
#pragma unroll
      for (int r = 0; r < 4; r++) {
        int mg = mstart + wm + mi * 16 + rbase + r;
        if (mg >= cnt) continue;
        float* crow = y + (size_t)(off0 + mg) * DD + ntile * 128;
#pragma unroll
        for (int ni = 0; ni < 4; ni++)
          crow[wn + ni * 16 + qm] = acc[mi][ni][r] + bv[ni];
      }
    }
  }
}

// ---------------- host ----------------
extern "C" void kernel_launch(void* const* d_in, const int* in_sizes, int n_in,
                              void* d_out, int out_size, void* d_ws, size_t ws_size,
                              hipStream_t stream) {
  const float* x   = (const float*)d_in[0];
  const int*  eidx = (const int*)d_in[1];
  const float* W1  = (const float*)d_in[2];
  const float* b1  = (const float*)d_in[3];
  const float* W2  = (const float*)d_in[4];
  const float* b2  = (const float*)d_in[5];
  const float* lng = (const float*)d_in[6];
  const float* lnb = (const float*)d_in[7];

  char* ws = (char*)d_ws;
  const size_t WT_SLOT_B = (size_t)EE * DD * HH * 2;   // 18874368 bytes per (l,w) slot

  // big layout (all 4 transposed weight slices resident):
  //   xf 0 (12582912) | h 12582912 (6291456) | a 18874368 (25165824) |
  //   Wt 44040192 (4*18874368=75497472) | y 119537664 (25165824) |
  //   inv 144703488 (16384) | meta 144719872 (1024)  -> need ~144.72 MB
  const size_t NEED_BIG = 144720896ull;
  bool big = ws_size >= NEED_BIG;

  float*  xf = (float*)(ws + 0);
  ushort* h  = (ushort*)(ws + 12582912);
  ushort* a  = (ushort*)(ws + 18874368);
  ushort* Wt = (ushort*)(ws + 44040192);
  float*  y;
  int*    inv;
  int*    meta;
  if (big) {
    y    = (float*)(ws + 119537664);
    inv  = (int*)(ws + 144703488);
    meta = (int*)(ws + 144719872);
  } else {
    // R3 fallback layout (single Wt slot, reused per gemm)
    y    = (float*)(ws + 62914560);
    inv  = (int*)(ws + 88080384);
    meta = (int*)(ws + 88096768);
  }

  if (big) {
    // all 4 weight transposes in one dispatch (576 tiles/slice x 16 slices)
    transpose_all_kernel<<<dim3(576, 16), 256, 0, stream>>>(W1, W2, Wt);
  }
  prep_kernel<<<1, 256, 0, stream>>>(eidx, inv, meta);

  for (int l = 0; l < LL; l++) {
    if (l == 0)
      ln_kernel<false, false><<<T_TOK / 4, 256, 0, stream>>>(
          x, y, lng, lnb, inv, h, xf);
    else
      ln_kernel<true, true><<<T_TOK / 4, 256, 0, stream>>>(
          x, y, lng + l * DD, lnb + l * DD, inv, h, xf);

    ushort* W1t;
    ushort* W2t;
    if (big) {
      W1t = Wt + (size_t)(l * 2 + 0) * (WT_SLOT_B / 2);
      W2t = Wt + (size_t)(l * 2 + 1) * (WT_SLOT_B / 2);
    } else {
      W1t = Wt;
      W2t = Wt;
      // W1 slice (E, D, H) fp32 -> Wt (E, H, D) bf16
      transpose_f32_bf16<<<dim3(HH / 64, DD / 64, EE), 256, 0, stream>>>(
          W1 + (size_t)l * EE * DD * HH, W1t, DD, HH);
    }
    gemm_kernel<DD, DD, HH, true><<<dim3(HH / 128, 35), 256, 0, stream>>>(
        h, W1t, b1 + l * EE * HH, (void*)a, meta);
    if (!big) {
      // W2 slice (E, H, D) fp32 -> Wt (E, D, H) bf16
      transpose_f32_bf16<<<dim3(DD / 64, HH / 64, EE), 256, 0, stream>>>(
          W2 + (size_t)l * EE * HH * DD, W2t, HH, DD);
    }
    gemm_kernel<HH, HH / 2, DD, false><<<dim3(DD / 128, 35, 2), 256, 0, stream>>>(
        a, W2t, b2 + l * EE * DD, (void*)y, meta);
  }

  store_kernel<<<T_TOK / 4, 256, 0, stream>>>(xf, y, inv, (float*)d_out);
}

// Round 8
// 367.806 us; speedup vs baseline: 1.2519x; 1.0062x over previous
//
#include <hip/hip_runtime.h>
#include <hip/hip_bf16.h>

// Problem constants
#define T_TOK 4096   // B*S
#define DD 768
#define HH 3072
#define EE 4
#define LL 2
#define NELT (T_TOK * DD)

typedef __attribute__((ext_vector_type(8))) short short8;
typedef __attribute__((ext_vector_type(4))) float f32x4;

__device__ __forceinline__ float bf2f(ushort u) { return __uint_as_float(((unsigned)u) << 16); }
__device__ __forceinline__ ushort f2bf(float f) {
  unsigned x = __float_as_uint(f);
  return (ushort)((x + 0x7fffu + ((x >> 16) & 1u)) >> 16); // RNE
}

__device__ __forceinline__ void gl2lds16(const void* g, void* l) {
  __builtin_amdgcn_global_load_lds((const __attribute__((address_space(1))) void*)g,
                                   (__attribute__((address_space(3))) void*)l, 16, 0, 0);
}

// ---------------- prep: bucket tokens by expert, 128-row tiles ----------------
// meta: [0..3]=expert offsets, [4]=total, [5]=ntiles, [8+t]=tile_expert, [96+t]=tile_mstart
__global__ __launch_bounds__(256) void prep_kernel(const int* __restrict__ eidx,
                                                   int* __restrict__ inv,
                                                   int* __restrict__ meta) {
  __shared__ int cnt[EE], cur[EE], offs[EE];
  int t = threadIdx.x;
  if (t < EE) { cnt[t] = 0; cur[t] = 0; }
  __syncthreads();
  for (int i = t; i < T_TOK; i += 256) atomicAdd(&cnt[eidx[i]], 1);
  __syncthreads();
  if (t == 0) {
    int off = 0, nt = 0;
    for (int e = 0; e < EE; e++) {
      meta[e] = off; offs[e] = off;
      int c = cnt[e];
      int n = (c + 127) >> 7;
      for (int k = 0; k < n; k++) { meta[8 + nt] = e; meta[96 + nt] = k << 7; nt++; }
      off += c;
    }
    meta[4] = off;
    meta[5] = nt;
  }
  __syncthreads();
  for (int i = t; i < T_TOK; i += 256) {
    int e = eidx[i];
    inv[i] = offs[e] + atomicAdd(&cur[e], 1);
  }
}

// ---------------- LayerNorm (wave/token), optional fused residual partial-sum ----------------
// HASY: v = x[tok] + y0[pos] + y1[pos];  WRITEX: xf[tok] = v.  Writes h[pos] = LN(v).
template <bool HASY, bool WRITEX>
__global__ __launch_bounds__(256) void ln_kernel(const float* __restrict__ x,
                                                 const float* __restrict__ y,
                                                 const float* __restrict__ g,
                                                 const float* __restrict__ b,
                                                 const int* __restrict__ inv,
                                                 ushort* __restrict__ h,
                                                 float* __restrict__ xf) {
  int wid = blockIdx.x * 4 + (threadIdx.x >> 6);
  int lane = threadIdx.x & 63;
  int pos = inv[wid];
  const float* xr = x + (size_t)wid * DD;
  const float* y0 = y + (size_t)pos * DD;
  const float* y1 = y0 + NELT;
  float v[12], s = 0.f, ss = 0.f;
#pragma unroll
  for (int i = 0; i < 12; i++) {
    int c = lane + i * 64;
    float vv = xr[c];
    if (HASY) vv += y0[c] + y1[c];
    if (WRITEX) xf[(size_t)wid * DD + c] = vv;
    v[i] = vv;
    s += vv; ss += vv * vv;
  }
#pragma unroll
  for (int o = 32; o; o >>= 1) { s += __shfl_xor(s, o, 64); ss += __shfl_xor(ss, o, 64); }
  float mu = s * (1.f / DD);
  float var = ss * (1.f / DD) - mu * mu;
  float rs = rsqrtf(var + 1e-6f);
  ushort* hr = h + (size_t)pos * DD;
#pragma unroll
  for (int i = 0; i < 12; i++) {
    int c = lane + i * 64;
    hr[c] = f2bf((v[i] - mu) * rs * g[c] + b[c]);
  }
}

// ---------------- final: out = xf + y0 + y1 (wave/token) ----------------
__global__ __launch_bounds__(256) void store_kernel(const float* __restrict__ xf,
                                                    const float* __restrict__ y,
                                                    const int* __restrict__ inv,
                                                    float* __restrict__ out) {
  int wid = blockIdx.x * 4 + (threadIdx.x >> 6);
  int lane = threadIdx.x & 63;
  int pos = inv[wid];
  const float* xr = xf + (size_t)wid * DD;
  const float* y0 = y + (size_t)pos * DD;
  const float* y1 = y0 + NELT;
  float* o = out + (size_t)wid * DD;
#pragma unroll
  for (int i = 0; i < 12; i++) {
    int c = lane + i * 64;
    o[c] = xr[c] + y0[c] + y1[c];
  }
}

// ---------------- fp32 (R,C) -> bf16 (C,R) transpose+downcast, batched over z ----------------
// (fallback path: per-layer, per-weight, z = expert)
__global__ __launch_bounds__(256) void transpose_f32_bf16(const float* __restrict__ src,
                                                          ushort* __restrict__ dst,
                                                          int R, int C) {
  __shared__ ushort tile[64][68];
  size_t mo = (size_t)blockIdx.z * R * C;
  src += mo;
  dst += mo;
  int c0 = blockIdx.x * 64, r0 = blockIdx.y * 64;
  int t = threadIdx.x;
  int tr = t >> 4;          // 0..15
  int tc = (t & 15) << 2;   // 0..60 step 4
#pragma unroll
  for (int i = 0; i < 4; i++) {
    int r = tr + i * 16;
    float4 v = *(const float4*)(src + (size_t)(r0 + r) * C + (c0 + tc));
    tile[r][tc] = f2bf(v.x); tile[r][tc + 1] = f2bf(v.y);
    tile[r][tc + 2] = f2bf(v.z); tile[r][tc + 3] = f2bf(v.w);
  }
  __syncthreads();
#pragma unroll
  for (int i = 0; i < 4; i++) {
    int c = tr + i * 16;
    ushort4 v;
    v.x = tile[tc][c]; v.y = tile[tc + 1][c]; v.z = tile[tc + 2][c]; v.w = tile[tc + 3][c];
    *(ushort4*)(dst + (size_t)(c0 + c) * R + (r0 + tc)) = v;
  }
}

// ---------------- ALL weight transposes in ONE dispatch (big-ws path) ----------------
// 128x128 tiles: 512B contiguous src reads, 256B contiguous+aligned dst writes per
// 32-lane group (kills the 2x HBM write amplification seen at 128B segments), and an
// XOR-swizzled flat LDS tile idx(r,c) = r*128 + (c ^ (((r>>2)&15)<<2)):
//   load  : ds_write_b64 (vector), covers all 32 banks evenly
//   store : ds_read_b32 gathers -> 16 banks 2-way (free, m136); each b32 feeds TWO dst rows.
// blockIdx.y = z in [0,16): l = z>>3, w12 = (z>>2)&1 (0:W1, 1:W2), e = z&3.
// blockIdx.x = b in [0,144): within-slice 128x128 tile, gx = C/128 tiles per row-band.
__global__ __launch_bounds__(256) void transpose_all_kernel(const float* __restrict__ W1,
                                                            const float* __restrict__ W2,
                                                            ushort* __restrict__ Wt) {
  __shared__ ushort tile[16384];   // 128 x 128 bf16, swizzled
  int z = blockIdx.y;
  int l = z >> 3, w12 = (z >> 2) & 1, e = z & 3;
  int R = w12 ? HH : DD, C = w12 ? DD : HH;
  const float* src = (w12 ? W2 : W1) + (size_t)(l * EE + e) * DD * HH;
  ushort* dst = Wt + ((size_t)(l * 2 + w12) * EE + e) * ((size_t)DD * HH);
  int gx = C >> 7;
  int b = blockIdx.x;
  int c0 = (b % gx) << 7, r0 = (b / gx) << 7;
  int t = threadIdx.x;

  // load: 16 iters; thread reads float4 src[r0+r][c0+4*c4], writes swizzled ushort4.
  int c4 = t & 31;           // which float4 of the 128-col row (32 x 16B = 512B)
  int rh = t >> 5;           // 0..7
#pragma unroll
  for (int it = 0; it < 16; it++) {
    int r = it * 8 + rh;
    float4 v = *(const float4*)(src + (size_t)(r0 + r) * C + c0 + c4 * 4);
    ushort4 u;
    u.x = f2bf(v.x); u.y = f2bf(v.y); u.z = f2bf(v.z); u.w = f2bf(v.w);
    int x = ((r >> 2) & 15) << 2;                 // XOR on c-bits 2..5 (keeps 4-contig, 8B align)
    *(ushort4*)(tile + r * 128 + ((c4 * 4) ^ x)) = u;
  }
  __syncthreads();

  // store: 8 iters; thread gathers 4 x b32 (rows c,c+1 interleaved), emits 2 ushort4 rows.
  // 32 rg-lanes x 8B = 256B contiguous, 256B-aligned per dst row.
  int rg = t & 31;
  int ch = t >> 5;           // 0..7
#pragma unroll
  for (int it = 0; it < 8; it++) {
    int c = it * 16 + ch * 2;
    uint w0[4];
#pragma unroll
    for (int j = 0; j < 4; j++) {
      int r = rg * 4 + j;
      int x = ((r >> 2) & 15) << 2;               // = (rg&15)<<2
      w0[j] = *(const uint*)(tile + r * 128 + (c ^ x));
    }
    ushort4 lo, hi;
    lo.x = (ushort)w0[0]; hi.x = (ushort)(w0[0] >> 16);
    lo.y = (ushort)w0[1]; hi.y = (ushort)(w0[1] >> 16);
    lo.z = (ushort)w0[2]; hi.z = (ushort)(w0[2] >> 16);
    lo.w = (ushort)w0[3]; hi.w = (ushort)(w0[3] >> 16);
    *(ushort4*)(dst + (size_t)(c0 + c) * R + r0 + rg * 4) = lo;
    *(ushort4*)(dst + (size_t)(c0 + c + 1) * R + r0 + rg * 4) = hi;
  }
}

// ---------------- grouped GEMM, 128M x 128N tile, BK=64, XOR-swizzled LDS (R3-verified) ----------------
// Double-buffered LDS + counted-vmcnt pipeline, 4 waves, 2 blocks/CU.
template <int KTOT, int KLEN, int NTOT, bool GELU>
__global__ __launch_bounds__(256, 2) void gemm_kernel(const ushort* __restrict__ A,
                                                      const ushort* __restrict__ Bt,
                                                      const float* __restrict__ bias,
                                                      void* __restrict__ Cout,
                                                      const int* __restrict__ meta) {
  // XCD-chunked bijective swizzle over the launched (x,y) grid, per z-slice.
  int gx = gridDim.x;
  int nwg = gx * gridDim.y;
  int wgid = blockIdx.y * gx + blockIdx.x;
  int sq = nwg >> 3, sr = nwg & 7;
  int xcd = wgid & 7, sidx = wgid >> 3;
  int sw = (xcd < sr ? xcd * (sq + 1) : sr * (sq + 1) + (xcd - sr) * sq) + sidx;
  int ntile = sw % gx;
  int ty = sw / gx;

  if (ty >= meta[5]) return;
  int e = meta[8 + ty];
  int mstart = meta[96 + ty];
  int off0 = meta[e];
  int cnt = meta[e + 1] - off0;
  int z = blockIdx.z;
  int kbegin = z * KLEN;

  // 64 KB LDS: 2 buffers x (As 128x64 + Bs 128x64) bf16.
  __shared__ __align__(16) ushort lds[32768];

  int tid = threadIdx.x;
  int w = tid >> 6, lane = tid & 63;

  // staging: row-group rr = lane>>3 (0..7); global chunk = (lane&7) ^ rr (XOR swizzle)
  // so LDS[r][c] holds global chunk (c ^ (r&7)). LDS dest = uniform base + lane*16.
  int rr = lane >> 3;
  int swz = ((lane & 7) ^ rr) * 8; // element offset of the 16B chunk this lane fetches
  const ushort* agp[4];
  const ushort* bgp[4];
  int aoff[4];
  int boff[4];
#pragma unroll
  for (int i = 0; i < 4; i++) {
    int r = w * 32 + i * 8;                       // uniform part of A row (0..127)
    int arow = off0 + min(mstart + r + rr, cnt - 1);
    agp[i] = A + (size_t)arow * KTOT + kbegin + swz;
    aoff[i] = r * 64 + lane * 8;                  // = uniform + lane*16B
  }
#pragma unroll
  for (int i = 0; i < 4; i++) {
    int r = w * 32 + i * 8;                       // B row (0..127)
    int brow = e * NTOT + ntile * 128 + r + rr;
    bgp[i] = Bt + (size_t)brow * KTOT + kbegin + swz;
    boff[i] = 8192 + r * 64 + lane * 8;
  }

  // wave grid 2x2: each wave owns 64M x 64N
  int wm = (w >> 1) * 64, wn = (w & 1) * 64;
  int qm = lane & 15;
  int quad = lane >> 4;
  int s7 = qm & 7;

  f32x4 acc[4][4];
#pragma unroll
  for (int mi = 0; mi < 4; mi++)
#pragma unroll
    for (int ni = 0; ni < 4; ni++) acc[mi][ni] = (f32x4){0.f, 0.f, 0.f, 0.f};

#define STAGE(nb, koff)                                            \
  do {                                                             \
    ushort* _b = lds + (nb) * 16384;                               \
    _Pragma("unroll")                                              \
    for (int _i = 0; _i < 4; _i++) gl2lds16(agp[_i] + (koff), _b + aoff[_i]); \
    _Pragma("unroll")                                              \
    for (int _i = 0; _i < 4; _i++) gl2lds16(bgp[_i] + (koff), _b + boff[_i]); \
  } while (0)

  constexpr int NSTEPS = KLEN / 64;
  STAGE(0, 0);                        // prologue: fill buffer 0
  asm volatile("" ::: "memory");      // pin prologue loads as the OLDEST vmcnt entries

#pragma unroll 1
  for (int s = 0; s < NSTEPS; ++s) {
    int curb = s & 1;
    if (s + 1 < NSTEPS) {
      STAGE(curb ^ 1, (s + 1) * 64);                  // prefetch next K-step
      asm volatile("s_waitcnt vmcnt(8)" ::: "memory"); // my 8 cur-buffer loads done; 8 stay in flight
    } else {
      asm volatile("s_waitcnt vmcnt(0)" ::: "memory");
    }
    __builtin_amdgcn_s_barrier();                      // all waves' cur-buffer staging visible
    asm volatile("" ::: "memory");

    const ushort* Asb = lds + curb * 16384;
    const ushort* Bsb = Asb + 8192;
#pragma unroll
    for (int h2 = 0; h2 < 2; h2++) {
      int lchunk = ((h2 * 4 + quad) ^ s7) * 8;    // un-swizzle
      short8 af[4], bfr[4];
#pragma unroll
      for (int mi = 0; mi < 4; mi++)
        af[mi] = *(const short8*)(Asb + (wm + mi * 16 + qm) * 64 + lchunk);
#pragma unroll
      for (int ni = 0; ni < 4; ni++)
        bfr[ni] = *(const short8*)(Bsb + (wn + ni * 16 + qm) * 64 + lchunk);
#pragma unroll
      for (int mi = 0; mi < 4; mi++)
#pragma unroll
        for (int ni = 0; ni < 4; ni++)
          acc[mi][ni] = __builtin_amdgcn_mfma_f32_16x16x32_bf16(af[mi], bfr[ni], acc[mi][ni], 0, 0, 0);
    }
    asm volatile("" ::: "memory");
    __builtin_amdgcn_s_barrier();                      // cur buffer free for overwrite next iter
    asm volatile("" ::: "memory");
  }
#undef STAGE

  // epilogue. C/D mapping: col = lane&15, row = quad*4 + reg
  int rbase = quad * 4;
  float bv[4];
#pragma unroll
  for (int ni = 0; ni < 4; ni++)
    bv[ni] = (!GELU && z != 0) ? 0.f : bias[e * NTOT + ntile * 128 + wn + ni * 16 + qm];

  if (GELU) {
    // bias+gelu -> LDS 128x128 bf16 -> coalesced 16B row stores (permuted space)
#pragma unroll
    for (int mi = 0; mi < 4; mi++)
#pragma unroll
      for (int ni = 0; ni < 4; ni++) {
        int c = wn + ni * 16 + qm;
#pragma unroll
        for (int r = 0; r < 4; r++) {
          float vv = acc[mi][ni][r] + bv[ni];
          vv = 0.5f * vv * (1.f + erff(vv * 0.70710678118f));
          lds[(wm + mi * 16 + rbase + r) * 128 + c] = f2bf(vv);
        }
      }
    __syncthreads();
    int row0 = tid >> 4;            // 0..15
    int cseg = (tid & 15) * 8;      // 16B chunks
    ushort* aout = (ushort*)Cout;
#pragma unroll
    for (int it = 0; it < 8; it++) {
      int row = it * 16 + row0;
      int mg = mstart + row;
      if (mg < cnt) {
        short8 v = *(const short8*)(lds + row * 128 + cseg);
        *(short8*)(aout + (size_t)(off0 + mg) * HH + ntile * 128 + cseg) = v;
      }
    }
  } else {
    // coalesced fp32 partial stores (permuted space), no atomics
    float* y = (float*)Cout + (size_t)z * NELT;
#pragma unroll
    for (int mi = 0; mi < 4; mi++) {
#pragma unroll
      for (int r = 0; r < 4; r++) {
        int mg = mstart + wm + mi * 16 + rbase + r;
        if (mg >= cnt) continue;
        float* crow = y + (size_t)(off0 + mg) * DD + ntile * 128;
#pragma unroll
        for (int ni = 0; ni < 4; ni++)
          crow[wn + ni * 16 + qm] = acc[mi][ni][r] + bv[ni];
      }
    }
  }
}

// ---------------- host ----------------
extern "C" void kernel_launch(void* const* d_in, const int* in_sizes, int n_in,
                              void* d_out, int out_size, void* d_ws, size_t ws_size,
                              hipStream_t stream) {
  const float* x   = (const float*)d_in[0];
  const int*  eidx = (const int*)d_in[1];
  const float* W1  = (const float*)d_in[2];
  const float* b1  = (const float*)d_in[3];
  const float* W2  = (const float*)d_in[4];
  const float* b2  = (const float*)d_in[5];
  const float* lng = (const float*)d_in[6];
  const float* lnb = (const float*)d_in[7];

  char* ws = (char*)d_ws;
  const size_t WT_SLOT_B = (size_t)EE * DD * HH * 2;   // 18874368 bytes per (l,w) slot

  // big layout (all 4 transposed weight slices resident):
  //   xf 0 (12582912) | h 12582912 (6291456) | a 18874368 (25165824) |
  //   Wt 44040192 (4*18874368=75497472) | y 119537664 (25165824) |
  //   inv 144703488 (16384) | meta 144719872 (1024)  -> need ~144.72 MB
  const size_t NEED_BIG = 144720896ull;
  bool big = ws_size >= NEED_BIG;

  float*  xf = (float*)(ws + 0);
  ushort* h  = (ushort*)(ws + 12582912);
  ushort* a  = (ushort*)(ws + 18874368);
  ushort* Wt = (ushort*)(ws + 44040192);
  float*  y;
  int*    inv;
  int*    meta;
  if (big) {
    y    = (float*)(ws + 119537664);
    inv  = (int*)(ws + 144703488);
    meta = (int*)(ws + 144719872);
  } else {
    // R3 fallback layout (single Wt slot, reused per gemm)
    y    = (float*)(ws + 62914560);
    inv  = (int*)(ws + 88080384);
    meta = (int*)(ws + 88096768);
  }

  if (big) {
    // all 4 weight transposes in one dispatch (144 128x128 tiles/slice x 16 slices)
    transpose_all_kernel<<<dim3(144, 16), 256, 0, stream>>>(W1, W2, Wt);
  }
  prep_kernel<<<1, 256, 0, stream>>>(eidx, inv, meta);

  for (int l = 0; l < LL; l++) {
    if (l == 0)
      ln_kernel<false, false><<<T_TOK / 4, 256, 0, stream>>>(
          x, y, lng, lnb, inv, h, xf);
    else
      ln_kernel<true, true><<<T_TOK / 4, 256, 0, stream>>>(
          x, y, lng + l * DD, lnb + l * DD, inv, h, xf);

    ushort* W1t;
    ushort* W2t;
    if (big) {
      W1t = Wt + (size_t)(l * 2 + 0) * (WT_SLOT_B / 2);
      W2t = Wt + (size_t)(l * 2 + 1) * (WT_SLOT_B / 2);
    } else {
      W1t = Wt;
      W2t = Wt;
      // W1 slice (E, D, H) fp32 -> Wt (E, H, D) bf16
      transpose_f32_bf16<<<dim3(HH / 64, DD / 64, EE), 256, 0, stream>>>(
          W1 + (size_t)l * EE * DD * HH, W1t, DD, HH);
    }
    gemm_kernel<DD, DD, HH, true><<<dim3(HH / 128, 35), 256, 0, stream>>>(
        h, W1t, b1 + l * EE * HH, (void*)a, meta);
    if (!big) {
      // W2 slice (E, H, D) fp32 -> Wt (E, D, H) bf16
      transpose_f32_bf16<<<dim3(DD / 64, HH / 64, EE), 256, 0, stream>>>(
          W2 + (size_t)l * EE * HH * DD, W2t, HH, DD);
    }
    gemm_kernel<HH, HH / 2, DD, false><<<dim3(DD / 128, 35, 2), 256, 0, stream>>>(
        a, W2t, b2 + l * EE * DD, (void*)y, meta);
  }

  store_kernel<<<T_TOK / 4, 256, 0, stream>>>(xf, y, inv, (float*)d_out);
}